// Round 6
// baseline (576.059 us; speedup 1.0000x reference)
//
#include <hip/hip_runtime.h>

#define HDIM 1024
#define TLEN 2048
#define NBATCH 16

typedef short bf16x8 __attribute__((ext_vector_type(8)));
typedef float floatx4 __attribute__((ext_vector_type(4)));
typedef unsigned short ushort_t;

__device__ __forceinline__ ushort_t f2bf(float x) {
  unsigned u = __float_as_uint(x);
  unsigned r = (u + 0x7FFFu + ((u >> 16) & 1u)) >> 16;
  return (ushort_t)r;
}
__device__ __forceinline__ float bf2f(ushort_t h) {
  return __uint_as_float(((unsigned)h) << 16);
}

#define TSTR 71     // epilogue/prep transpose stride (64x64 tiles)

// ---------------- prep: split A into bf16 h/m/l (+transposed); init V col0 / U row0 ----------------
__global__ __launch_bounds__(256) void prep(const float* __restrict__ A,
    const float* __restrict__ Bv, const float* __restrict__ Cv,
    ushort_t* __restrict__ Ah, ushort_t* __restrict__ Am, ushort_t* __restrict__ Al,
    ushort_t* __restrict__ ATh, ushort_t* __restrict__ ATm, ushort_t* __restrict__ ATl,
    float* __restrict__ Vc, float* __restrict__ U) {
  __shared__ ushort_t Lt[3 * 64 * TSTR];
  const int tid = threadIdx.x;
  if (blockIdx.x >= 256) {  // init blocks
    int i = (blockIdx.x - 256) * 256 + tid;
    if (i < HDIM) Vc[i] = Bv[i];
    else U[i - HDIM] = Cv[i - HDIM];
    return;
  }
  const int row0 = (blockIdx.x >> 4) * 64, col0 = (blockIdx.x & 15) * 64;
  const int r = tid >> 2, q = tid & 3;
  ushort_t hs[16], ms[16], ls[16];
#pragma unroll
  for (int c4 = 0; c4 < 4; ++c4) {
    float4 a = *(const float4*)&A[(row0 + r) * HDIM + col0 + q * 16 + c4 * 4];
    float av[4] = {a.x, a.y, a.z, a.w};
#pragma unroll
    for (int i = 0; i < 4; ++i) {
      float z = av[i];
      ushort_t h = f2bf(z); float r1 = z - bf2f(h);
      ushort_t mq = f2bf(r1); float r2 = r1 - bf2f(mq);
      ushort_t lq = f2bf(r2);
      hs[c4 * 4 + i] = h; ms[c4 * 4 + i] = mq; ls[c4 * 4 + i] = lq;
    }
  }
  size_t go = (size_t)(row0 + r) * HDIM + col0 + q * 16;
  *(uint4*)&Ah[go] = ((uint4*)hs)[0]; *(uint4*)&Ah[go + 8] = ((uint4*)hs)[1];
  *(uint4*)&Am[go] = ((uint4*)ms)[0]; *(uint4*)&Am[go + 8] = ((uint4*)ms)[1];
  *(uint4*)&Al[go] = ((uint4*)ls)[0]; *(uint4*)&Al[go + 8] = ((uint4*)ls)[1];
#pragma unroll
  for (int i = 0; i < 16; ++i) {
    int c = q * 16 + i;
    Lt[0 * 64 * TSTR + r * TSTR + c] = hs[i];
    Lt[1 * 64 * TSTR + r * TSTR + c] = ms[i];
    Lt[2 * 64 * TSTR + r * TSTR + c] = ls[i];
  }
  __syncthreads();
  const int c = tid >> 2, q2 = tid & 3;
  ushort_t* dsts[3] = {ATh, ATm, ATl};
#pragma unroll
  for (int s = 0; s < 3; ++s) {
    ushort_t tmp[16];
#pragma unroll
    for (int rr = 0; rr < 16; ++rr) tmp[rr] = Lt[s * 64 * TSTR + (q2 * 16 + rr) * TSTR + c];
    size_t gt = (size_t)(col0 + c) * HDIM + row0 + q2 * 16;
    *(uint4*)&dsts[s][gt] = ((uint4*)tmp)[0];
    *(uint4*)&dsts[s][gt + 8] = ((uint4*)tmp)[1];
  }
}

// ---------------- Z = X*X, 64x64 tiles, LDS-FREE main loop (direct global->VGPR frags) ----------------
// SIX: 6 cross terms (reads l splits) else 4 (h/m).  WRITEL: emit l splits of Z.
// MODE 0 tail: V col1 = A*Bv (fp32); MODE 1: V cols NC..2NC-1 = P*V[0:NC];
// MODE 2: U rows NC..2NC-1 = U[0:NC]*P (transposed splits).
template <int MODE, int NC, bool SIX, bool WRITEL>
__global__ __launch_bounds__(256) void sq_mfma(
    const ushort_t* __restrict__ Xh, const ushort_t* __restrict__ Xm,
    const ushort_t* __restrict__ Xl,
    const ushort_t* __restrict__ XTh, const ushort_t* __restrict__ XTm,
    const ushort_t* __restrict__ XTl,
    ushort_t* __restrict__ Zh, ushort_t* __restrict__ Zm, ushort_t* __restrict__ Zl,
    ushort_t* __restrict__ ZTh, ushort_t* __restrict__ ZTm, ushort_t* __restrict__ ZTl,
    const float* __restrict__ Af, const float* __restrict__ Bvf,
    float* __restrict__ VU) {
  __shared__ ushort_t sm[3 * 64 * TSTR];  // epilogue transpose only
  const int tid = threadIdx.x;

  if (blockIdx.x >= 256) {  // ---- tail blocks: 256 blocks -> 1024 waves ----
    const int tb = blockIdx.x - 256;
    const int wv = tb * 4 + (tid >> 6);
    const int lane = tid & 63;
    if (MODE == 0) {
      float acc = 0.f;
      for (int k = lane; k < HDIM; k += 64) acc += Af[(size_t)wv * HDIM + k] * Bvf[k];
      for (int off = 32; off; off >>= 1) acc += __shfl_down(acc, off);
      if (lane == 0) VU[HDIM + wv] = acc;
    } else {
      const ushort_t* Ph = (MODE == 1) ? Xh : XTh;
      const ushort_t* Pm = (MODE == 1) ? Xm : XTm;
      float acc[NC];
#pragma unroll
      for (int n = 0; n < NC; ++n) acc[n] = 0.f;
      for (int k = lane; k < HDIM; k += 64) {
        float a = bf2f(Ph[(size_t)wv * HDIM + k]) + bf2f(Pm[(size_t)wv * HDIM + k]);
#pragma unroll
        for (int n = 0; n < NC; ++n) acc[n] += a * VU[(size_t)n * HDIM + k];
      }
#pragma unroll
      for (int n = 0; n < NC; ++n) {
        float s = acc[n];
        for (int off = 32; off; off >>= 1) s += __shfl_down(s, off);
        if (lane == 0) VU[(size_t)(NC + n) * HDIM + wv] = s;
      }
    }
    return;
  }

  // ---- squaring blocks: 16x16 grid of 64x64 tiles, XCD-rectangle swizzle ----
  const int bb = blockIdx.x;
  const int xcd = bb & 7, slot = bb >> 3;
  const int tr = 4 * (xcd >> 1) + (slot >> 3);
  const int tc = 8 * (xcd & 1) + (slot & 7);
  const int row0 = tr * 64, col0 = tc * 64;

  const int w = tid >> 6, l = tid & 63, li = l & 15, quad = l >> 4;

  // fragment addresses: A-frag natural in row-major splits, B-frag natural in transposed splits
  const size_t aoff = (size_t)(row0 + w * 16 + li) * HDIM + quad * 8;
  size_t boff[4];
#pragma unroll
  for (int j = 0; j < 4; ++j)
    boff[j] = (size_t)(col0 + j * 16 + li) * HDIM + quad * 8;

  floatx4 accs[4];
#pragma unroll
  for (int j = 0; j < 4; ++j) accs[j] = (floatx4){0.f, 0.f, 0.f, 0.f};

  bf16x8 ah0, am0, al0, bh0[4], bm0[4], bl0[4];
  bf16x8 ah1, am1, al1, bh1[4], bm1[4], bl1[4];

#define LOADF(AH_, AM_, AL_, BH_, BM_, BL_, KOFF)                              \
  {                                                                            \
    AH_ = *(const bf16x8*)&Xh[aoff + (KOFF)];                                  \
    AM_ = *(const bf16x8*)&Xm[aoff + (KOFF)];                                  \
    if (SIX) AL_ = *(const bf16x8*)&Xl[aoff + (KOFF)];                         \
    _Pragma("unroll") for (int j = 0; j < 4; ++j) {                            \
      BH_[j] = *(const bf16x8*)&XTh[boff[j] + (KOFF)];                         \
      BM_[j] = *(const bf16x8*)&XTm[boff[j] + (KOFF)];                         \
      if (SIX) BL_[j] = *(const bf16x8*)&XTl[boff[j] + (KOFF)];                \
    }                                                                          \
  }

#define DO_TERMS(AH_, AM_, AL_, BH_, BM_, BL_)                                 \
  {                                                                            \
    _Pragma("unroll") for (int j = 0; j < 4; ++j) {                            \
      floatx4 a = accs[j];                                                     \
      a = __builtin_amdgcn_mfma_f32_16x16x32_bf16(AH_, BH_[j], a, 0, 0, 0);    \
      a = __builtin_amdgcn_mfma_f32_16x16x32_bf16(AH_, BM_[j], a, 0, 0, 0);    \
      a = __builtin_amdgcn_mfma_f32_16x16x32_bf16(AM_, BH_[j], a, 0, 0, 0);    \
      a = __builtin_amdgcn_mfma_f32_16x16x32_bf16(AM_, BM_[j], a, 0, 0, 0);    \
      if (SIX) {                                                               \
        a = __builtin_amdgcn_mfma_f32_16x16x32_bf16(AH_, BL_[j], a, 0, 0, 0);  \
        a = __builtin_amdgcn_mfma_f32_16x16x32_bf16(AL_, BH_[j], a, 0, 0, 0);  \
      }                                                                        \
      accs[j] = a;                                                             \
    }                                                                          \
  }

  LOADF(ah0, am0, al0, bh0, bm0, bl0, 0);
  for (int k0 = 0; k0 < HDIM; k0 += 64) {
    LOADF(ah1, am1, al1, bh1, bm1, bl1, k0 + 32);
    DO_TERMS(ah0, am0, al0, bh0, bm0, bl0);
    const int kq = (k0 + 64 < HDIM) ? k0 + 64 : 0;  // last prefetch: harmless refetch
    LOADF(ah0, am0, al0, bh0, bm0, bl0, kq);
    DO_TERMS(ah1, am1, al1, bh1, bm1, bl1);
  }
#undef LOADF
#undef DO_TERMS

  // ---- epilogue: split, store row-major + LDS-transposed splits ----
#pragma unroll
  for (int j = 0; j < 4; ++j) {
#pragma unroll
    for (int e = 0; e < 4; ++e) {
      float z = accs[j][e];
      int rl = w * 16 + quad * 4 + e;
      int cl = j * 16 + li;
      size_t go = (size_t)(row0 + rl) * HDIM + col0 + cl;
      ushort_t h = f2bf(z); float r1 = z - bf2f(h);
      ushort_t mq = f2bf(r1);
      Zh[go] = h; Zm[go] = mq;
      sm[0 * 64 * TSTR + rl * TSTR + cl] = h;
      sm[1 * 64 * TSTR + rl * TSTR + cl] = mq;
      if (WRITEL) {
        ushort_t lq = f2bf(r1 - bf2f(mq));
        Zl[go] = lq;
        sm[2 * 64 * TSTR + rl * TSTR + cl] = lq;
      }
    }
  }
  __syncthreads();
  const int c = tid >> 2, q2 = tid & 3;
  ushort_t* dsts[3] = {ZTh, ZTm, ZTl};
  const int npass = WRITEL ? 3 : 2;
#pragma unroll
  for (int s = 0; s < 3; ++s) {
    if (s >= npass) break;
    ushort_t tmp[16];
#pragma unroll
    for (int rr = 0; rr < 16; ++rr) tmp[rr] = sm[s * 64 * TSTR + (q2 * 16 + rr) * TSTR + c];
    size_t gt = (size_t)(col0 + c) * HDIM + row0 + q2 * 16;
    *(uint4*)&dsts[s][gt] = ((uint4*)tmp)[0];
    *(uint4*)&dsts[s][gt + 8] = ((uint4*)tmp)[1];
  }
}

// ---------------- U extension: rows dst..dst+7 = rows dst-8..dst-1 x A^512 ----------------
__global__ __launch_bounds__(256) void utail8(const ushort_t* __restrict__ PTh,
                                              const ushort_t* __restrict__ PTm,
                                              float* __restrict__ U, int dstbase) {
  const int wv = blockIdx.x * 4 + (threadIdx.x >> 6);
  const int lane = threadIdx.x & 63;
  float acc[8];
#pragma unroll
  for (int m = 0; m < 8; ++m) acc[m] = 0.f;
  const float* Usrc = U + (size_t)(dstbase - 8) * HDIM;
  for (int k = lane; k < HDIM; k += 64) {
    float a = bf2f(PTh[(size_t)wv * HDIM + k]) + bf2f(PTm[(size_t)wv * HDIM + k]);
#pragma unroll
    for (int m = 0; m < 8; ++m) acc[m] += a * Usrc[(size_t)m * HDIM + k];
  }
#pragma unroll
  for (int m = 0; m < 8; ++m) {
    float s = acc[m];
    for (int off = 32; off; off >>= 1) s += __shfl_down(s, off);
    if (lane == 0) U[(size_t)(dstbase + m) * HDIM + wv] = s;
  }
}

// ---------------- K[m] = U row (m>>6) . V col (m&63) ----------------
__global__ __launch_bounds__(256) void wavedotK(const float* __restrict__ U,
                                                const float* __restrict__ Vc,
                                                float* __restrict__ Km) {
  int wv = (blockIdx.x * blockDim.x + threadIdx.x) >> 6;
  int lane = threadIdx.x & 63;
  if (wv >= 32 * 64) return;
  int mr = wv >> 6;
  int nc = wv & 63;
  float s = 0.f;
  for (int k = lane; k < HDIM; k += 64) s += U[mr * HDIM + k] * Vc[nc * HDIM + k];
  for (int off = 32; off; off >>= 1) s += __shfl_down(s, off);
  if (lane == 0) Km[wv] = s;
}

// ---------------- causal conv, LDS-tiled ----------------
__global__ __launch_bounds__(256) void convk2(const float* __restrict__ u,
                                              const float* __restrict__ Km,
                                              const float* __restrict__ Dv,
                                              float* __restrict__ y) {
  __shared__ float ks[256];
  __shared__ float us[512];
  const int tt = threadIdx.x;
  const int t0 = blockIdx.x * 256;
  const int b = blockIdx.y;
  const float* ub = u + (size_t)b * TLEN;
  const int t = t0 + tt;
  float s = Dv[0] * ub[t];
  for (int mc = 0; mc <= t0; mc += 256) {
    __syncthreads();
    ks[tt] = Km[mc + tt];
    int w0 = t0 - mc - 255;
    int g0 = w0 + tt;
    us[tt] = (g0 >= 0) ? ub[g0] : 0.f;
    int g1 = w0 + 256 + tt;
    us[256 + tt] = (g1 < TLEN) ? ub[g1] : 0.f;
    __syncthreads();
    if (mc < t0) {
#pragma unroll 4
      for (int r = 0; r < 256; r += 4) {
        float4 kv = *(const float4*)&ks[r];
        s += kv.x * us[tt - r + 255];
        s += kv.y * us[tt - r + 254];
        s += kv.z * us[tt - r + 253];
        s += kv.w * us[tt - r + 252];
      }
    } else {
      for (int r = 0; r <= tt; ++r) s += ks[r] * us[tt - r + 255];
    }
  }
  y[(size_t)b * TLEN + t] = s;
}

extern "C" void kernel_launch(void* const* d_in, const int* in_sizes, int n_in,
                              void* d_out, int out_size, void* d_ws, size_t ws_size,
                              hipStream_t stream) {
  const float* u  = (const float*)d_in[0];
  const float* A  = (const float*)d_in[1];
  const float* Bv = (const float*)d_in[2];
  const float* Cv = (const float*)d_in[3];
  const float* Dv = (const float*)d_in[4];
  float* out = (float*)d_out;

  char* wsb = (char*)d_ws;
  size_t off = 0;
  ushort_t* S[2][6];
  for (int s = 0; s < 2; ++s)
    for (int a = 0; a < 6; ++a) { S[s][a] = (ushort_t*)(wsb + off); off += (size_t)2 << 20; }
  float* Vc = (float*)(wsb + off); off += 64 * HDIM * 4;
  float* U  = (float*)(wsb + off); off += 32 * HDIM * 4;
  float* Km = (float*)(wsb + off); off += TLEN * 4;

  const dim3 gsq(512);  // 256 squaring blocks (swizzled) + 256 tail blocks

#define SQ(MODE, NC, SIX, WRL, IN, OUT, VU)                                    \
  sq_mfma<MODE, NC, SIX, WRL><<<gsq, 256, 0, stream>>>(                        \
      S[IN][0], S[IN][1], S[IN][2], S[IN][3], S[IN][4], S[IN][5],              \
      S[OUT][0], S[OUT][1], S[OUT][2], S[OUT][3], S[OUT][4], S[OUT][5],        \
      A, Bv, VU)

  prep<<<dim3(264), 256, 0, stream>>>(A, Bv, Cv,
      S[0][0], S[0][1], S[0][2], S[0][3], S[0][4], S[0][5], Vc, U);

  SQ(0, 1,  true,  true,  0, 1, Vc);  // A^2    ; tail: V col1 = A*Bv
  SQ(1, 2,  true,  true,  1, 0, Vc);  // A^4    ; tail: V cols 2,3    (A^2)
  SQ(1, 4,  true,  true,  0, 1, Vc);  // A^8    ; tail: V cols 4..7   (A^4)
  SQ(1, 8,  true,  false, 1, 0, Vc);  // A^16   ; tail: V cols 8..15  (A^8)
  SQ(1, 16, false, false, 0, 1, Vc);  // A^32   ; tail: V cols 16..31 (A^16)
  SQ(1, 32, false, false, 1, 0, Vc);  // A^64   ; tail: V cols 32..63 (A^32)
  SQ(2, 1,  false, false, 0, 1, U);   // A^128  ; tail: U row 1       (A^64)
  SQ(2, 2,  false, false, 1, 0, U);   // A^256  ; tail: U rows 2,3    (A^128)
  SQ(2, 4,  false, false, 0, 1, U);   // A^512  ; tail: U rows 4..7   (A^256)
#undef SQ

  // U rows 8..31 via A^512 (S[1] transposed splits), sequential x3
  utail8<<<dim3(256), 256, 0, stream>>>(S[1][3], S[1][4], U, 8);
  utail8<<<dim3(256), 256, 0, stream>>>(S[1][3], S[1][4], U, 16);
  utail8<<<dim3(256), 256, 0, stream>>>(S[1][3], S[1][4], U, 24);

  wavedotK<<<dim3(512), 256, 0, stream>>>(U, Vc, Km);
  convk2<<<dim3(TLEN / 256, NBATCH), 256, 0, stream>>>(u, Km, Dv, out);
}

// Round 7
// 488.112 us; speedup vs baseline: 1.1802x; 1.1802x over previous
//
#include <hip/hip_runtime.h>

#define HDIM 1024
#define TLEN 2048
#define NBATCH 16

typedef short bf16x8 __attribute__((ext_vector_type(8)));
typedef float floatx4 __attribute__((ext_vector_type(4)));
typedef unsigned short ushort_t;

__device__ __forceinline__ ushort_t f2bf(float x) {
  unsigned u = __float_as_uint(x);
  unsigned r = (u + 0x7FFFu + ((u >> 16) & 1u)) >> 16;
  return (ushort_t)r;
}
__device__ __forceinline__ float bf2f(ushort_t h) {
  return __uint_as_float(((unsigned)h) << 16);
}

#define TSTR 71     // epilogue/prep transpose stride (64x64 tiles)

#define MFMA(A_, B_, C_) __builtin_amdgcn_mfma_f32_16x16x32_bf16(A_, B_, C_, 0, 0, 0)

// ---------------- prep: split A into bf16 h/m/l (+transposed); init V col0 / U row0 ----------------
__global__ __launch_bounds__(256) void prep(const float* __restrict__ A,
    const float* __restrict__ Bv, const float* __restrict__ Cv,
    ushort_t* __restrict__ Ah, ushort_t* __restrict__ Am, ushort_t* __restrict__ Al,
    ushort_t* __restrict__ ATh, ushort_t* __restrict__ ATm, ushort_t* __restrict__ ATl,
    float* __restrict__ Vc, float* __restrict__ U) {
  __shared__ ushort_t Lt[3 * 64 * TSTR];
  const int tid = threadIdx.x;
  if (blockIdx.x >= 256) {  // init blocks
    int i = (blockIdx.x - 256) * 256 + tid;
    if (i < HDIM) Vc[i] = Bv[i];
    else U[i - HDIM] = Cv[i - HDIM];
    return;
  }
  const int row0 = (blockIdx.x >> 4) * 64, col0 = (blockIdx.x & 15) * 64;
  const int r = tid >> 2, q = tid & 3;
  ushort_t hs[16], ms[16], ls[16];
#pragma unroll
  for (int c4 = 0; c4 < 4; ++c4) {
    float4 a = *(const float4*)&A[(row0 + r) * HDIM + col0 + q * 16 + c4 * 4];
    float av[4] = {a.x, a.y, a.z, a.w};
#pragma unroll
    for (int i = 0; i < 4; ++i) {
      float z = av[i];
      ushort_t h = f2bf(z); float r1 = z - bf2f(h);
      ushort_t mq = f2bf(r1); float r2 = r1 - bf2f(mq);
      ushort_t lq = f2bf(r2);
      hs[c4 * 4 + i] = h; ms[c4 * 4 + i] = mq; ls[c4 * 4 + i] = lq;
    }
  }
  size_t go = (size_t)(row0 + r) * HDIM + col0 + q * 16;
  *(uint4*)&Ah[go] = ((uint4*)hs)[0]; *(uint4*)&Ah[go + 8] = ((uint4*)hs)[1];
  *(uint4*)&Am[go] = ((uint4*)ms)[0]; *(uint4*)&Am[go + 8] = ((uint4*)ms)[1];
  *(uint4*)&Al[go] = ((uint4*)ls)[0]; *(uint4*)&Al[go + 8] = ((uint4*)ls)[1];
#pragma unroll
  for (int i = 0; i < 16; ++i) {
    int c = q * 16 + i;
    Lt[0 * 64 * TSTR + r * TSTR + c] = hs[i];
    Lt[1 * 64 * TSTR + r * TSTR + c] = ms[i];
    Lt[2 * 64 * TSTR + r * TSTR + c] = ls[i];
  }
  __syncthreads();
  const int c = tid >> 2, q2 = tid & 3;
  ushort_t* dsts[3] = {ATh, ATm, ATl};
#pragma unroll
  for (int s = 0; s < 3; ++s) {
    ushort_t tmp[16];
#pragma unroll
    for (int rr = 0; rr < 16; ++rr) tmp[rr] = Lt[s * 64 * TSTR + (q2 * 16 + rr) * TSTR + c];
    size_t gt = (size_t)(col0 + c) * HDIM + row0 + q2 * 16;
    *(uint4*)&dsts[s][gt] = ((uint4*)tmp)[0];
    *(uint4*)&dsts[s][gt + 8] = ((uint4*)tmp)[1];
  }
}

// ---------------- Z = X*X, 64x64 tiles, double-buffered LDS staging + fused V/U tail ----------------
// SIX: 6 cross terms, BK=32; else 4 terms, BK=64.  WRITEL: emit l splits of Z.
// MODE 0 tail: V col1 = A*Bv (fp32); MODE 1: V cols NC..2NC-1 = P*V[0:NC];
// MODE 2: U rows NC..2NC-1 = U[0:NC]*P (transposed splits).
template <int MODE, int NC, bool SIX, bool WRITEL>
__global__ __launch_bounds__(256) void sq_mfma(
    const ushort_t* __restrict__ Xh, const ushort_t* __restrict__ Xm,
    const ushort_t* __restrict__ Xl,
    const ushort_t* __restrict__ XTh, const ushort_t* __restrict__ XTm,
    const ushort_t* __restrict__ XTl,
    ushort_t* __restrict__ Zh, ushort_t* __restrict__ Zm, ushort_t* __restrict__ Zl,
    ushort_t* __restrict__ ZTh, ushort_t* __restrict__ ZTm, ushort_t* __restrict__ ZTl,
    const float* __restrict__ Af, const float* __restrict__ Bvf,
    float* __restrict__ VU) {
  constexpr int STR   = SIX ? 40 : 70;   // staged row stride (bank-spread, ~2-way max)
  constexpr int BK    = SIX ? 32 : 64;
  constexpr int SLAB  = 64 * STR;
  constexpr int BUFSZ = (SIX ? 6 : 4) * SLAB;
  __shared__ ushort_t sm[2 * BUFSZ];     // 6T: 61.4 KB, 4T: 71.7 KB (2 blocks/CU both)
  const int tid = threadIdx.x;

  if (blockIdx.x >= 256) {  // ---- tail blocks: 256 blocks -> 1024 waves ----
    const int tb = blockIdx.x - 256;
    const int wv = tb * 4 + (tid >> 6);
    const int lane = tid & 63;
    if (MODE == 0) {
      float acc = 0.f;
      for (int k = lane; k < HDIM; k += 64) acc += Af[(size_t)wv * HDIM + k] * Bvf[k];
      for (int off = 32; off; off >>= 1) acc += __shfl_down(acc, off);
      if (lane == 0) VU[HDIM + wv] = acc;
    } else {
      const ushort_t* Ph = (MODE == 1) ? Xh : XTh;
      const ushort_t* Pm = (MODE == 1) ? Xm : XTm;
      float acc[NC];
#pragma unroll
      for (int n = 0; n < NC; ++n) acc[n] = 0.f;
      for (int k = lane; k < HDIM; k += 64) {
        float a = bf2f(Ph[(size_t)wv * HDIM + k]) + bf2f(Pm[(size_t)wv * HDIM + k]);
#pragma unroll
        for (int n = 0; n < NC; ++n) acc[n] += a * VU[(size_t)n * HDIM + k];
      }
#pragma unroll
      for (int n = 0; n < NC; ++n) {
        float s = acc[n];
        for (int off = 32; off; off >>= 1) s += __shfl_down(s, off);
        if (lane == 0) VU[(size_t)(NC + n) * HDIM + wv] = s;
      }
    }
    return;
  }

  // ---- squaring blocks: 16x16 grid of 64x64 tiles, XCD-rectangle swizzle ----
  const int bb = blockIdx.x;
  const int xcd = bb & 7, slot = bb >> 3;
  const int tr = 4 * (xcd >> 1) + (slot >> 3);
  const int tc = 8 * (xcd & 1) + (slot & 7);
  const int row0 = tr * 64, col0 = tc * 64;
  const int w = tid >> 6, l = tid & 63, li = l & 15, quad = l >> 4;

  floatx4 accs[4];
#pragma unroll
  for (int j = 0; j < 4; ++j) accs[j] = (floatx4){0.f, 0.f, 0.f, 0.f};

  // slab bases within one buffer
  constexpr int AH = 0, AM = SLAB, AL = 2 * SLAB;
  constexpr int BH = (SIX ? 3 : 2) * SLAB, BM = (SIX ? 4 : 3) * SLAB, BL = 5 * SLAB;

  const int sr = tid >> 2, sq4 = tid & 3;
  const size_t gA = (size_t)(row0 + sr) * HDIM;
  const size_t gB = (size_t)(col0 + sr) * HDIM;

  if constexpr (!SIX) {
    // ---- 4-term path, BK=64, double-buffered ----
    const int so0 = sr * STR + sq4 * 16, so1 = so0 + 8;
    const size_t ga = gA + sq4 * 16, gb = gB + sq4 * 16;
    uint4 rAh0, rAh1, rAm0, rAm1, rBh0, rBh1, rBm0, rBm1;
#define LOAD4T(K)                                                              \
    { size_t k_ = (K);                                                         \
      rAh0 = *(const uint4*)&Xh[ga + k_];  rAh1 = *(const uint4*)&Xh[ga + k_ + 8]; \
      rAm0 = *(const uint4*)&Xm[ga + k_];  rAm1 = *(const uint4*)&Xm[ga + k_ + 8]; \
      rBh0 = *(const uint4*)&XTh[gb + k_]; rBh1 = *(const uint4*)&XTh[gb + k_ + 8]; \
      rBm0 = *(const uint4*)&XTm[gb + k_]; rBm1 = *(const uint4*)&XTm[gb + k_ + 8]; }
#define WRITE4T(BUF)                                                           \
    { ushort_t* b_ = &sm[(BUF) * BUFSZ];                                       \
      *(uint4*)&b_[AH + so0] = rAh0; *(uint4*)&b_[AH + so1] = rAh1;            \
      *(uint4*)&b_[AM + so0] = rAm0; *(uint4*)&b_[AM + so1] = rAm1;            \
      *(uint4*)&b_[BH + so0] = rBh0; *(uint4*)&b_[BH + so1] = rBh1;            \
      *(uint4*)&b_[BM + so0] = rBm0; *(uint4*)&b_[BM + so1] = rBm1; }
    LOAD4T(0);
    WRITE4T(0);
    LOAD4T(BK);
    __syncthreads();
    int cur = 0;
    for (int k0 = 0; k0 < HDIM; k0 += BK) {
      const ushort_t* b = &sm[cur * BUFSZ];
#pragma unroll
      for (int kh = 0; kh < 2; ++kh) {
        const int ko = kh * 32;
        const int ao = (w * 16 + li) * STR + ko + quad * 8;
        bf16x8 ah = *(const bf16x8*)&b[AH + ao];
        bf16x8 am = *(const bf16x8*)&b[AM + ao];
#pragma unroll
        for (int j = 0; j < 4; ++j) {
          const int bo = (j * 16 + li) * STR + ko + quad * 8;
          bf16x8 bh = *(const bf16x8*)&b[BH + bo];
          bf16x8 bm = *(const bf16x8*)&b[BM + bo];
          floatx4 a = accs[j];
          a = MFMA(ah, bh, a); a = MFMA(ah, bm, a);
          a = MFMA(am, bh, a); a = MFMA(am, bm, a);
          accs[j] = a;
        }
      }
      if (k0 + BK < HDIM) {
        WRITE4T(cur ^ 1);
        LOAD4T((k0 + 2 * BK < HDIM) ? (size_t)(k0 + 2 * BK) : 0);
        __syncthreads();
        cur ^= 1;
      }
    }
#undef LOAD4T
#undef WRITE4T
  } else {
    // ---- 6-term path, BK=32, double-buffered ----
    const int so = sr * STR + sq4 * 8;
    const size_t ga = gA + sq4 * 8, gb = gB + sq4 * 8;
    uint4 rAh, rAm, rAl, rBh, rBm, rBl;
#define LOAD6T(K)                                                              \
    { size_t k_ = (K);                                                         \
      rAh = *(const uint4*)&Xh[ga + k_];  rAm = *(const uint4*)&Xm[ga + k_];   \
      rAl = *(const uint4*)&Xl[ga + k_];                                       \
      rBh = *(const uint4*)&XTh[gb + k_]; rBm = *(const uint4*)&XTm[gb + k_];  \
      rBl = *(const uint4*)&XTl[gb + k_]; }
#define WRITE6T(BUF)                                                           \
    { ushort_t* b_ = &sm[(BUF) * BUFSZ];                                       \
      *(uint4*)&b_[AH + so] = rAh; *(uint4*)&b_[AM + so] = rAm;                \
      *(uint4*)&b_[AL + so] = rAl;                                             \
      *(uint4*)&b_[BH + so] = rBh; *(uint4*)&b_[BM + so] = rBm;                \
      *(uint4*)&b_[BL + so] = rBl; }
    LOAD6T(0);
    WRITE6T(0);
    LOAD6T(BK);
    __syncthreads();
    int cur = 0;
    for (int k0 = 0; k0 < HDIM; k0 += BK) {
      const ushort_t* b = &sm[cur * BUFSZ];
      const int ao = (w * 16 + li) * STR + quad * 8;
      bf16x8 ah = *(const bf16x8*)&b[AH + ao];
      bf16x8 am = *(const bf16x8*)&b[AM + ao];
      bf16x8 al = *(const bf16x8*)&b[AL + ao];
#pragma unroll
      for (int j = 0; j < 4; ++j) {
        const int bo = (j * 16 + li) * STR + quad * 8;
        bf16x8 bh = *(const bf16x8*)&b[BH + bo];
        bf16x8 bm = *(const bf16x8*)&b[BM + bo];
        bf16x8 bl = *(const bf16x8*)&b[BL + bo];
        floatx4 a = accs[j];
        a = MFMA(ah, bh, a); a = MFMA(ah, bm, a);
        a = MFMA(am, bh, a); a = MFMA(am, bm, a);
        a = MFMA(ah, bl, a); a = MFMA(al, bh, a);
        accs[j] = a;
      }
      if (k0 + BK < HDIM) {
        WRITE6T(cur ^ 1);
        LOAD6T((k0 + 2 * BK < HDIM) ? (size_t)(k0 + 2 * BK) : 0);
        __syncthreads();
        cur ^= 1;
      }
    }
#undef LOAD6T
#undef WRITE6T
  }

  // ---- epilogue: split, store row-major + LDS-transposed splits ----
  __syncthreads();
#pragma unroll
  for (int j = 0; j < 4; ++j) {
#pragma unroll
    for (int e = 0; e < 4; ++e) {
      float z = accs[j][e];
      int rl = w * 16 + quad * 4 + e;
      int cl = j * 16 + li;
      size_t go = (size_t)(row0 + rl) * HDIM + col0 + cl;
      ushort_t h = f2bf(z); float r1 = z - bf2f(h);
      ushort_t mq = f2bf(r1);
      Zh[go] = h; Zm[go] = mq;
      sm[0 * 64 * TSTR + rl * TSTR + cl] = h;
      sm[1 * 64 * TSTR + rl * TSTR + cl] = mq;
      if (WRITEL) {
        ushort_t lq = f2bf(r1 - bf2f(mq));
        Zl[go] = lq;
        sm[2 * 64 * TSTR + rl * TSTR + cl] = lq;
      }
    }
  }
  __syncthreads();
  const int c = tid >> 2, q2 = tid & 3;
  ushort_t* dsts[3] = {ZTh, ZTm, ZTl};
  const int npass = WRITEL ? 3 : 2;
#pragma unroll
  for (int s = 0; s < 3; ++s) {
    if (s >= npass) break;
    ushort_t tmp[16];
#pragma unroll
    for (int rr = 0; rr < 16; ++rr) tmp[rr] = sm[s * 64 * TSTR + (q2 * 16 + rr) * TSTR + c];
    size_t gt = (size_t)(col0 + c) * HDIM + row0 + q2 * 16;
    *(uint4*)&dsts[s][gt] = ((uint4*)tmp)[0];
    *(uint4*)&dsts[s][gt + 8] = ((uint4*)tmp)[1];
  }
}

// ---------------- U extension: rows dst..dst+7 = rows dst-8..dst-1 x A^512 ----------------
__global__ __launch_bounds__(256) void utail8(const ushort_t* __restrict__ PTh,
                                              const ushort_t* __restrict__ PTm,
                                              float* __restrict__ U, int dstbase) {
  const int wv = blockIdx.x * 4 + (threadIdx.x >> 6);
  const int lane = threadIdx.x & 63;
  float acc[8];
#pragma unroll
  for (int m = 0; m < 8; ++m) acc[m] = 0.f;
  const float* Usrc = U + (size_t)(dstbase - 8) * HDIM;
  for (int k = lane; k < HDIM; k += 64) {
    float a = bf2f(PTh[(size_t)wv * HDIM + k]) + bf2f(PTm[(size_t)wv * HDIM + k]);
#pragma unroll
    for (int m = 0; m < 8; ++m) acc[m] += a * Usrc[(size_t)m * HDIM + k];
  }
#pragma unroll
  for (int m = 0; m < 8; ++m) {
    float s = acc[m];
    for (int off = 32; off; off >>= 1) s += __shfl_down(s, off);
    if (lane == 0) U[(size_t)(dstbase + m) * HDIM + wv] = s;
  }
}

// ---------------- K[m] = U row (m>>6) . V col (m&63) ----------------
__global__ __launch_bounds__(256) void wavedotK(const float* __restrict__ U,
                                                const float* __restrict__ Vc,
                                                float* __restrict__ Km) {
  int wv = (blockIdx.x * blockDim.x + threadIdx.x) >> 6;
  int lane = threadIdx.x & 63;
  if (wv >= 32 * 64) return;
  int mr = wv >> 6;
  int nc = wv & 63;
  float s = 0.f;
  for (int k = lane; k < HDIM; k += 64) s += U[mr * HDIM + k] * Vc[nc * HDIM + k];
  for (int off = 32; off; off >>= 1) s += __shfl_down(s, off);
  if (lane == 0) Km[wv] = s;
}

// ---------------- causal conv, LDS-tiled ----------------
__global__ __launch_bounds__(256) void convk2(const float* __restrict__ u,
                                              const float* __restrict__ Km,
                                              const float* __restrict__ Dv,
                                              float* __restrict__ y) {
  __shared__ float ks[256];
  __shared__ float us[512];
  const int tt = threadIdx.x;
  const int t0 = blockIdx.x * 256;
  const int b = blockIdx.y;
  const float* ub = u + (size_t)b * TLEN;
  const int t = t0 + tt;
  float s = Dv[0] * ub[t];
  for (int mc = 0; mc <= t0; mc += 256) {
    __syncthreads();
    ks[tt] = Km[mc + tt];
    int w0 = t0 - mc - 255;
    int g0 = w0 + tt;
    us[tt] = (g0 >= 0) ? ub[g0] : 0.f;
    int g1 = w0 + 256 + tt;
    us[256 + tt] = (g1 < TLEN) ? ub[g1] : 0.f;
    __syncthreads();
    if (mc < t0) {
#pragma unroll 4
      for (int r = 0; r < 256; r += 4) {
        float4 kv = *(const float4*)&ks[r];
        s += kv.x * us[tt - r + 255];
        s += kv.y * us[tt - r + 254];
        s += kv.z * us[tt - r + 253];
        s += kv.w * us[tt - r + 252];
      }
    } else {
      for (int r = 0; r <= tt; ++r) s += ks[r] * us[tt - r + 255];
    }
  }
  y[(size_t)b * TLEN + t] = s;
}

extern "C" void kernel_launch(void* const* d_in, const int* in_sizes, int n_in,
                              void* d_out, int out_size, void* d_ws, size_t ws_size,
                              hipStream_t stream) {
  const float* u  = (const float*)d_in[0];
  const float* A  = (const float*)d_in[1];
  const float* Bv = (const float*)d_in[2];
  const float* Cv = (const float*)d_in[3];
  const float* Dv = (const float*)d_in[4];
  float* out = (float*)d_out;

  char* wsb = (char*)d_ws;
  size_t off = 0;
  ushort_t* S[2][6];
  for (int s = 0; s < 2; ++s)
    for (int a = 0; a < 6; ++a) { S[s][a] = (ushort_t*)(wsb + off); off += (size_t)2 << 20; }
  float* Vc = (float*)(wsb + off); off += 64 * HDIM * 4;
  float* U  = (float*)(wsb + off); off += 32 * HDIM * 4;
  float* Km = (float*)(wsb + off); off += TLEN * 4;

  const dim3 gsq(512);  // 256 squaring blocks (swizzled) + 256 tail blocks

#define SQ(MODE, NC, SIX, WRL, IN, OUT, VU)                                    \
  sq_mfma<MODE, NC, SIX, WRL><<<gsq, 256, 0, stream>>>(                        \
      S[IN][0], S[IN][1], S[IN][2], S[IN][3], S[IN][4], S[IN][5],              \
      S[OUT][0], S[OUT][1], S[OUT][2], S[OUT][3], S[OUT][4], S[OUT][5],        \
      A, Bv, VU)

  prep<<<dim3(264), 256, 0, stream>>>(A, Bv, Cv,
      S[0][0], S[0][1], S[0][2], S[0][3], S[0][4], S[0][5], Vc, U);

  SQ(0, 1,  true,  true,  0, 1, Vc);  // A^2    ; tail: V col1 = A*Bv
  SQ(1, 2,  true,  true,  1, 0, Vc);  // A^4    ; tail: V cols 2,3    (A^2)
  SQ(1, 4,  true,  true,  0, 1, Vc);  // A^8    ; tail: V cols 4..7   (A^4)
  SQ(1, 8,  true,  false, 1, 0, Vc);  // A^16   ; tail: V cols 8..15  (A^8)
  SQ(1, 16, false, false, 0, 1, Vc);  // A^32   ; tail: V cols 16..31 (A^16)
  SQ(1, 32, false, false, 1, 0, Vc);  // A^64   ; tail: V cols 32..63 (A^32)
  SQ(2, 1,  false, false, 0, 1, U);   // A^128  ; tail: U row 1       (A^64)
  SQ(2, 2,  false, false, 1, 0, U);   // A^256  ; tail: U rows 2,3    (A^128)
  SQ(2, 4,  false, false, 0, 1, U);   // A^512  ; tail: U rows 4..7   (A^256)
#undef SQ

  // U rows 8..31 via A^512 (S[1] transposed splits), sequential x3
  utail8<<<dim3(256), 256, 0, stream>>>(S[1][3], S[1][4], U, 8);
  utail8<<<dim3(256), 256, 0, stream>>>(S[1][3], S[1][4], U, 16);
  utail8<<<dim3(256), 256, 0, stream>>>(S[1][3], S[1][4], U, 24);

  wavedotK<<<dim3(512), 256, 0, stream>>>(U, Vc, Km);
  convk2<<<dim3(TLEN / 256, NBATCH), 256, 0, stream>>>(u, Km, Dv, out);
}

// Round 8
// 337.749 us; speedup vs baseline: 1.7056x; 1.4452x over previous
//
#include <hip/hip_runtime.h>

#define HDIM 1024
#define TLEN 2048
#define NBATCH 16

typedef short bf16x8 __attribute__((ext_vector_type(8)));
typedef float floatx4 __attribute__((ext_vector_type(4)));
typedef unsigned short ushort_t;

__device__ __forceinline__ ushort_t f2bf(float x) {
  unsigned u = __float_as_uint(x);
  unsigned r = (u + 0x7FFFu + ((u >> 16) & 1u)) >> 16;
  return (ushort_t)r;
}
__device__ __forceinline__ float bf2f(ushort_t h) {
  return __uint_as_float(((unsigned)h) << 16);
}

#define LSTR 40     // staged slab row stride (32 + 8 pad) in bf16 elems
#define TSTR 71     // transpose stride (64x64 tiles)

#define MFMA(A_, B_, C_) __builtin_amdgcn_mfma_f32_16x16x32_bf16(A_, B_, C_, 0, 0, 0)

// ---------------- prep: split A into bf16 h/m/l (+transposed); init V col0 / U row0 ----------------
__global__ __launch_bounds__(256) void prep(const float* __restrict__ A,
    const float* __restrict__ Bv, const float* __restrict__ Cv,
    ushort_t* __restrict__ Ah, ushort_t* __restrict__ Am, ushort_t* __restrict__ Al,
    ushort_t* __restrict__ ATh, ushort_t* __restrict__ ATm, ushort_t* __restrict__ ATl,
    float* __restrict__ Vc, float* __restrict__ U) {
  __shared__ ushort_t Lt[3 * 64 * TSTR];
  const int tid = threadIdx.x;
  if (blockIdx.x >= 256) {  // init blocks
    int i = (blockIdx.x - 256) * 256 + tid;
    if (i < HDIM) Vc[i] = Bv[i];
    else U[i - HDIM] = Cv[i - HDIM];
    return;
  }
  const int row0 = (blockIdx.x >> 4) * 64, col0 = (blockIdx.x & 15) * 64;
  const int r = tid >> 2, q = tid & 3;
  ushort_t hs[16], ms[16], ls[16];
#pragma unroll
  for (int c4 = 0; c4 < 4; ++c4) {
    float4 a = *(const float4*)&A[(row0 + r) * HDIM + col0 + q * 16 + c4 * 4];
    float av[4] = {a.x, a.y, a.z, a.w};
#pragma unroll
    for (int i = 0; i < 4; ++i) {
      float z = av[i];
      ushort_t h = f2bf(z); float r1 = z - bf2f(h);
      ushort_t mq = f2bf(r1); float r2 = r1 - bf2f(mq);
      ushort_t lq = f2bf(r2);
      hs[c4 * 4 + i] = h; ms[c4 * 4 + i] = mq; ls[c4 * 4 + i] = lq;
    }
  }
  size_t go = (size_t)(row0 + r) * HDIM + col0 + q * 16;
  *(uint4*)&Ah[go] = ((uint4*)hs)[0]; *(uint4*)&Ah[go + 8] = ((uint4*)hs)[1];
  *(uint4*)&Am[go] = ((uint4*)ms)[0]; *(uint4*)&Am[go + 8] = ((uint4*)ms)[1];
  *(uint4*)&Al[go] = ((uint4*)ls)[0]; *(uint4*)&Al[go + 8] = ((uint4*)ls)[1];
#pragma unroll
  for (int i = 0; i < 16; ++i) {
    int c = q * 16 + i;
    Lt[0 * 64 * TSTR + r * TSTR + c] = hs[i];
    Lt[1 * 64 * TSTR + r * TSTR + c] = ms[i];
    Lt[2 * 64 * TSTR + r * TSTR + c] = ls[i];
  }
  __syncthreads();
  const int c = tid >> 2, q2 = tid & 3;
  ushort_t* dsts[3] = {ATh, ATm, ATl};
#pragma unroll
  for (int s = 0; s < 3; ++s) {
    ushort_t tmp[16];
#pragma unroll
    for (int rr = 0; rr < 16; ++rr) tmp[rr] = Lt[s * 64 * TSTR + (q2 * 16 + rr) * TSTR + c];
    size_t gt = (size_t)(col0 + c) * HDIM + row0 + q2 * 16;
    *(uint4*)&dsts[s][gt] = ((uint4*)tmp)[0];
    *(uint4*)&dsts[s][gt + 8] = ((uint4*)tmp)[1];
  }
}

// ---------------- Zp[kh] partial = X*X over k-half, 64x64 tiles (round-5 loop) + fused tails ----------------
// SIX: 6 cross terms (reads l splits) else 4 (h/m).
// MODE 0 tail: V col1 = A*Bv; MODE 1: V cols NC..2NC-1 = P*V[0:NC]; MODE 2: U rows NC..2NC-1.
template <int MODE, int NC, bool SIX>
__global__ __launch_bounds__(256) void sq_part(
    const ushort_t* __restrict__ Xh, const ushort_t* __restrict__ Xm,
    const ushort_t* __restrict__ Xl,
    const ushort_t* __restrict__ XTh, const ushort_t* __restrict__ XTm,
    const ushort_t* __restrict__ XTl,
    float* __restrict__ Zp0, float* __restrict__ Zp1,
    const float* __restrict__ Af, const float* __restrict__ Bvf,
    float* __restrict__ VU) {
  constexpr int SLAB = 64 * LSTR;
  constexpr int NSLAB = SIX ? 6 : 4;
  __shared__ ushort_t sm[NSLAB * SLAB];  // 6T: 30.7 KB, 4T: 20.5 KB
  const int tid = threadIdx.x;

  if (blockIdx.x >= 512) {  // ---- tail blocks: 256 blocks -> 1024 waves ----
    const int tb = blockIdx.x - 512;
    const int wv = tb * 4 + (tid >> 6);
    const int lane = tid & 63;
    if (MODE == 0) {
      float acc = 0.f;
      for (int k = lane; k < HDIM; k += 64) acc += Af[(size_t)wv * HDIM + k] * Bvf[k];
      for (int off = 32; off; off >>= 1) acc += __shfl_down(acc, off);
      if (lane == 0) VU[HDIM + wv] = acc;
    } else {
      const ushort_t* Ph = (MODE == 1) ? Xh : XTh;
      const ushort_t* Pm = (MODE == 1) ? Xm : XTm;
      float acc[NC];
#pragma unroll
      for (int n = 0; n < NC; ++n) acc[n] = 0.f;
      for (int k = lane; k < HDIM; k += 64) {
        float a = bf2f(Ph[(size_t)wv * HDIM + k]) + bf2f(Pm[(size_t)wv * HDIM + k]);
#pragma unroll
        for (int n = 0; n < NC; ++n) acc[n] += a * VU[(size_t)n * HDIM + k];
      }
#pragma unroll
      for (int n = 0; n < NC; ++n) {
        float s = acc[n];
        for (int off = 32; off; off >>= 1) s += __shfl_down(s, off);
        if (lane == 0) VU[(size_t)(NC + n) * HDIM + wv] = s;
      }
    }
    return;
  }

  // ---- squaring blocks: 256 tiles x 2 k-halves, XCD-rectangle swizzle ----
  const int bb = blockIdx.x;
  const int xcd = bb & 7, slot = bb >> 3;         // slot 0..63
  const int kh = slot & 1;
  const int tr = 4 * (xcd >> 1) + (slot >> 4);
  const int tc = 8 * (xcd & 1) + ((slot >> 1) & 7);
  const int row0 = tr * 64, col0 = tc * 64;
  const int kbase = kh * (HDIM / 2), kend = kbase + HDIM / 2;

  constexpr int AH = 0, AM = SLAB, AL = 2 * SLAB;
  constexpr int BH = (SIX ? 3 : 2) * SLAB, BM = (SIX ? 4 : 3) * SLAB, BL = 5 * SLAB;

  const int w = tid >> 6, l = tid & 63, li = l & 15, quad = l >> 4;
  const int sr = tid >> 2, sq4 = tid & 3;

  floatx4 acc0 = {0.f, 0.f, 0.f, 0.f}, acc1 = acc0, acc2 = acc0, acc3 = acc0;

  const int aoff = (w * 16 + li) * LSTR + quad * 8;
  const int b0o = (0 * 16 + li) * LSTR + quad * 8;
  const int b1o = (1 * 16 + li) * LSTR + quad * 8;
  const int b2o = (2 * 16 + li) * LSTR + quad * 8;
  const int b3o = (3 * 16 + li) * LSTR + quad * 8;
  const int soff = sr * LSTR + sq4 * 8;
  const size_t gA = (size_t)(row0 + sr) * HDIM + sq4 * 8 + kbase;
  const size_t gB = (size_t)(col0 + sr) * HDIM + sq4 * 8 + kbase;

  uint4 pa0 = *(const uint4*)&Xh[gA], pa1 = *(const uint4*)&Xm[gA];
  uint4 pb0 = *(const uint4*)&XTh[gB], pb1 = *(const uint4*)&XTm[gB];
  uint4 pa2, pb2;
  if (SIX) { pa2 = *(const uint4*)&Xl[gA]; pb2 = *(const uint4*)&XTl[gB]; }

  for (int k0 = kbase; k0 < kend; k0 += 32) {
    __syncthreads();
    *(uint4*)&sm[AH + soff] = pa0;
    *(uint4*)&sm[AM + soff] = pa1;
    *(uint4*)&sm[BH + soff] = pb0;
    *(uint4*)&sm[BM + soff] = pb1;
    if (SIX) {
      *(uint4*)&sm[AL + soff] = pa2;
      *(uint4*)&sm[BL + soff] = pb2;
    }
    __syncthreads();
    if (k0 + 32 < kend) {
      const size_t ko = (size_t)(k0 + 32 - kbase);
      pa0 = *(const uint4*)&Xh[gA + ko];
      pa1 = *(const uint4*)&Xm[gA + ko];
      pb0 = *(const uint4*)&XTh[gB + ko];
      pb1 = *(const uint4*)&XTm[gB + ko];
      if (SIX) {
        pa2 = *(const uint4*)&Xl[gA + ko];
        pb2 = *(const uint4*)&XTl[gB + ko];
      }
    }
    bf16x8 ah = *(const bf16x8*)&sm[AH + aoff];
    bf16x8 am = *(const bf16x8*)&sm[AM + aoff];
    bf16x8 al;
    if (SIX) al = *(const bf16x8*)&sm[AL + aoff];
    {
      bf16x8 bh = *(const bf16x8*)&sm[BH + b0o];
      bf16x8 bm = *(const bf16x8*)&sm[BM + b0o];
      acc0 = MFMA(ah, bh, acc0); acc0 = MFMA(ah, bm, acc0);
      acc0 = MFMA(am, bh, acc0); acc0 = MFMA(am, bm, acc0);
      if (SIX) {
        bf16x8 bl = *(const bf16x8*)&sm[BL + b0o];
        acc0 = MFMA(ah, bl, acc0); acc0 = MFMA(al, bh, acc0);
      }
    }
    {
      bf16x8 bh = *(const bf16x8*)&sm[BH + b1o];
      bf16x8 bm = *(const bf16x8*)&sm[BM + b1o];
      acc1 = MFMA(ah, bh, acc1); acc1 = MFMA(ah, bm, acc1);
      acc1 = MFMA(am, bh, acc1); acc1 = MFMA(am, bm, acc1);
      if (SIX) {
        bf16x8 bl = *(const bf16x8*)&sm[BL + b1o];
        acc1 = MFMA(ah, bl, acc1); acc1 = MFMA(al, bh, acc1);
      }
    }
    {
      bf16x8 bh = *(const bf16x8*)&sm[BH + b2o];
      bf16x8 bm = *(const bf16x8*)&sm[BM + b2o];
      acc2 = MFMA(ah, bh, acc2); acc2 = MFMA(ah, bm, acc2);
      acc2 = MFMA(am, bh, acc2); acc2 = MFMA(am, bm, acc2);
      if (SIX) {
        bf16x8 bl = *(const bf16x8*)&sm[BL + b2o];
        acc2 = MFMA(ah, bl, acc2); acc2 = MFMA(al, bh, acc2);
      }
    }
    {
      bf16x8 bh = *(const bf16x8*)&sm[BH + b3o];
      bf16x8 bm = *(const bf16x8*)&sm[BM + b3o];
      acc3 = MFMA(ah, bh, acc3); acc3 = MFMA(ah, bm, acc3);
      acc3 = MFMA(am, bh, acc3); acc3 = MFMA(am, bm, acc3);
      if (SIX) {
        bf16x8 bl = *(const bf16x8*)&sm[BL + b3o];
        acc3 = MFMA(ah, bl, acc3); acc3 = MFMA(al, bh, acc3);
      }
    }
  }

  // ---- epilogue: plain fp32 partial stores (coalesced), no LDS ----
  float* __restrict__ Zp = kh ? Zp1 : Zp0;
  floatx4 accs[4] = {acc0, acc1, acc2, acc3};
#pragma unroll
  for (int j = 0; j < 4; ++j)
#pragma unroll
    for (int e = 0; e < 4; ++e) {
      int rl = w * 16 + quad * 4 + e;
      int cl = j * 16 + li;
      Zp[(size_t)(row0 + rl) * HDIM + col0 + cl] = accs[j][e];
    }
}

// ---------------- finalize: Z = Zp0+Zp1 -> bf16 splits (row-major + transposed) ----------------
template <bool WRITEL>
__global__ __launch_bounds__(256) void finalize(
    const float* __restrict__ Zp0, const float* __restrict__ Zp1,
    ushort_t* __restrict__ Zh, ushort_t* __restrict__ Zm, ushort_t* __restrict__ Zl,
    ushort_t* __restrict__ ZTh, ushort_t* __restrict__ ZTm, ushort_t* __restrict__ ZTl) {
  __shared__ ushort_t Lt[3 * 64 * TSTR];
  const int tid = threadIdx.x;
  const int row0 = (blockIdx.x >> 4) * 64, col0 = (blockIdx.x & 15) * 64;
  const int r = tid >> 2, q = tid & 3;
  ushort_t hs[16], ms[16], ls[16];
#pragma unroll
  for (int c4 = 0; c4 < 4; ++c4) {
    size_t gi = (size_t)(row0 + r) * HDIM + col0 + q * 16 + c4 * 4;
    float4 a = *(const float4*)&Zp0[gi];
    float4 b = *(const float4*)&Zp1[gi];
    float av[4] = {a.x + b.x, a.y + b.y, a.z + b.z, a.w + b.w};
#pragma unroll
    for (int i = 0; i < 4; ++i) {
      float z = av[i];
      ushort_t h = f2bf(z); float r1 = z - bf2f(h);
      ushort_t mq = f2bf(r1);
      hs[c4 * 4 + i] = h; ms[c4 * 4 + i] = mq;
      if (WRITEL) ls[c4 * 4 + i] = f2bf(r1 - bf2f(mq));
    }
  }
  size_t go = (size_t)(row0 + r) * HDIM + col0 + q * 16;
  *(uint4*)&Zh[go] = ((uint4*)hs)[0]; *(uint4*)&Zh[go + 8] = ((uint4*)hs)[1];
  *(uint4*)&Zm[go] = ((uint4*)ms)[0]; *(uint4*)&Zm[go + 8] = ((uint4*)ms)[1];
  if (WRITEL) { *(uint4*)&Zl[go] = ((uint4*)ls)[0]; *(uint4*)&Zl[go + 8] = ((uint4*)ls)[1]; }
#pragma unroll
  for (int i = 0; i < 16; ++i) {
    int c = q * 16 + i;
    Lt[0 * 64 * TSTR + r * TSTR + c] = hs[i];
    Lt[1 * 64 * TSTR + r * TSTR + c] = ms[i];
    if (WRITEL) Lt[2 * 64 * TSTR + r * TSTR + c] = ls[i];
  }
  __syncthreads();
  const int c = tid >> 2, q2 = tid & 3;
  ushort_t* dsts[3] = {ZTh, ZTm, ZTl};
  const int npass = WRITEL ? 3 : 2;
#pragma unroll
  for (int s = 0; s < 3; ++s) {
    if (s >= npass) break;
    ushort_t tmp[16];
#pragma unroll
    for (int rr = 0; rr < 16; ++rr) tmp[rr] = Lt[s * 64 * TSTR + (q2 * 16 + rr) * TSTR + c];
    size_t gt = (size_t)(col0 + c) * HDIM + row0 + q2 * 16;
    *(uint4*)&dsts[s][gt] = ((uint4*)tmp)[0];
    *(uint4*)&dsts[s][gt + 8] = ((uint4*)tmp)[1];
  }
}

// ---------------- U extension: rows dst..dst+7 = rows dst-8..dst-1 x A^512 ----------------
__global__ __launch_bounds__(256) void utail8(const ushort_t* __restrict__ PTh,
                                              const ushort_t* __restrict__ PTm,
                                              float* __restrict__ U, int dstbase) {
  const int wv = blockIdx.x * 4 + (threadIdx.x >> 6);
  const int lane = threadIdx.x & 63;
  float acc[8];
#pragma unroll
  for (int m = 0; m < 8; ++m) acc[m] = 0.f;
  const float* Usrc = U + (size_t)(dstbase - 8) * HDIM;
  for (int k = lane; k < HDIM; k += 64) {
    float a = bf2f(PTh[(size_t)wv * HDIM + k]) + bf2f(PTm[(size_t)wv * HDIM + k]);
#pragma unroll
    for (int m = 0; m < 8; ++m) acc[m] += a * Usrc[(size_t)m * HDIM + k];
  }
#pragma unroll
  for (int m = 0; m < 8; ++m) {
    float s = acc[m];
    for (int off = 32; off; off >>= 1) s += __shfl_down(s, off);
    if (lane == 0) U[(size_t)(dstbase + m) * HDIM + wv] = s;
  }
}

// ---------------- K[m] = U row (m>>6) . V col (m&63) ----------------
__global__ __launch_bounds__(256) void wavedotK(const float* __restrict__ U,
                                                const float* __restrict__ Vc,
                                                float* __restrict__ Km) {
  int wv = (blockIdx.x * blockDim.x + threadIdx.x) >> 6;
  int lane = threadIdx.x & 63;
  if (wv >= 32 * 64) return;
  int mr = wv >> 6;
  int nc = wv & 63;
  float s = 0.f;
  for (int k = lane; k < HDIM; k += 64) s += U[mr * HDIM + k] * Vc[nc * HDIM + k];
  for (int off = 32; off; off >>= 1) s += __shfl_down(s, off);
  if (lane == 0) Km[wv] = s;
}

// ---------------- causal conv, LDS-tiled ----------------
__global__ __launch_bounds__(256) void convk2(const float* __restrict__ u,
                                              const float* __restrict__ Km,
                                              const float* __restrict__ Dv,
                                              float* __restrict__ y) {
  __shared__ float ks[256];
  __shared__ float us[512];
  const int tt = threadIdx.x;
  const int t0 = blockIdx.x * 256;
  const int b = blockIdx.y;
  const float* ub = u + (size_t)b * TLEN;
  const int t = t0 + tt;
  float s = Dv[0] * ub[t];
  for (int mc = 0; mc <= t0; mc += 256) {
    __syncthreads();
    ks[tt] = Km[mc + tt];
    int w0 = t0 - mc - 255;
    int g0 = w0 + tt;
    us[tt] = (g0 >= 0) ? ub[g0] : 0.f;
    int g1 = w0 + 256 + tt;
    us[256 + tt] = (g1 < TLEN) ? ub[g1] : 0.f;
    __syncthreads();
    if (mc < t0) {
#pragma unroll 4
      for (int r = 0; r < 256; r += 4) {
        float4 kv = *(const float4*)&ks[r];
        s += kv.x * us[tt - r + 255];
        s += kv.y * us[tt - r + 254];
        s += kv.z * us[tt - r + 253];
        s += kv.w * us[tt - r + 252];
      }
    } else {
      for (int r = 0; r <= tt; ++r) s += ks[r] * us[tt - r + 255];
    }
  }
  y[(size_t)b * TLEN + t] = s;
}

extern "C" void kernel_launch(void* const* d_in, const int* in_sizes, int n_in,
                              void* d_out, int out_size, void* d_ws, size_t ws_size,
                              hipStream_t stream) {
  const float* u  = (const float*)d_in[0];
  const float* A  = (const float*)d_in[1];
  const float* Bv = (const float*)d_in[2];
  const float* Cv = (const float*)d_in[3];
  const float* Dv = (const float*)d_in[4];
  float* out = (float*)d_out;

  char* wsb = (char*)d_ws;
  size_t off = 0;
  ushort_t* S[2][6];
  for (int s = 0; s < 2; ++s)
    for (int a = 0; a < 6; ++a) { S[s][a] = (ushort_t*)(wsb + off); off += (size_t)2 << 20; }
  float* Zp0 = (float*)(wsb + off); off += (size_t)HDIM * HDIM * 4;
  float* Zp1 = (float*)(wsb + off); off += (size_t)HDIM * HDIM * 4;
  float* Vc = (float*)(wsb + off); off += 64 * HDIM * 4;
  float* U  = (float*)(wsb + off); off += 32 * HDIM * 4;
  float* Km = (float*)(wsb + off); off += TLEN * 4;

  const dim3 gsq(768);  // 512 split-k squaring blocks + 256 tail blocks

#define SQ(MODE, NC, SIX, WRL, IN, OUT, VU)                                    \
  sq_part<MODE, NC, SIX><<<gsq, 256, 0, stream>>>(                             \
      S[IN][0], S[IN][1], S[IN][2], S[IN][3], S[IN][4], S[IN][5],              \
      Zp0, Zp1, A, Bv, VU);                                                    \
  finalize<WRL><<<dim3(256), 256, 0, stream>>>(                                \
      Zp0, Zp1,                                                                \
      S[OUT][0], S[OUT][1], S[OUT][2], S[OUT][3], S[OUT][4], S[OUT][5])

  prep<<<dim3(264), 256, 0, stream>>>(A, Bv, Cv,
      S[0][0], S[0][1], S[0][2], S[0][3], S[0][4], S[0][5], Vc, U);

  SQ(0, 1,  true,  true,  0, 1, Vc);  // A^2    ; tail: V col1 = A*Bv
  SQ(1, 2,  true,  true,  1, 0, Vc);  // A^4    ; tail: V cols 2,3    (A^2)
  SQ(1, 4,  true,  true,  0, 1, Vc);  // A^8    ; tail: V cols 4..7   (A^4)
  SQ(1, 8,  true,  false, 1, 0, Vc);  // A^16   ; tail: V cols 8..15  (A^8)
  SQ(1, 16, false, false, 0, 1, Vc);  // A^32   ; tail: V cols 16..31 (A^16)
  SQ(1, 32, false, false, 1, 0, Vc);  // A^64   ; tail: V cols 32..63 (A^32)
  SQ(2, 1,  false, false, 0, 1, U);   // A^128  ; tail: U row 1       (A^64)
  SQ(2, 2,  false, false, 1, 0, U);   // A^256  ; tail: U rows 2,3    (A^128)
  SQ(2, 4,  false, false, 0, 1, U);   // A^512  ; tail: U rows 4..7   (A^256)
#undef SQ

  // U rows 8..31 via A^512 (S[1] transposed splits), sequential x3
  utail8<<<dim3(256), 256, 0, stream>>>(S[1][3], S[1][4], U, 8);
  utail8<<<dim3(256), 256, 0, stream>>>(S[1][3], S[1][4], U, 16);
  utail8<<<dim3(256), 256, 0, stream>>>(S[1][3], S[1][4], U, 24);

  wavedotK<<<dim3(512), 256, 0, stream>>>(U, Vc, Km);
  convk2<<<dim3(TLEN / 256, NBATCH), 256, 0, stream>>>(u, Km, Dv, out);
}